// Round 2
// baseline (4278.803 us; speedup 1.0000x reference)
//
#include <hip/hip_runtime.h>
#include <cstdint>

#define H 64

__device__ __forceinline__ float wave_sum(float v) {
  #pragma unroll
  for (int off = 32; off > 0; off >>= 1)
    v += __shfl_xor(v, off, 64);
  return v;
}

// ---- degree count: deg[dst] += 1 over edges ----
__global__ __launch_bounds__(256) void deg_kernel(const int* __restrict__ ei,
                                                  float* __restrict__ deg, int E) {
  int stride = gridDim.x * blockDim.x;
  for (int e = blockIdx.x * blockDim.x + threadIdx.x; e < E; e += stride) {
    int d = ei[E + e];
    atomicAdd(&deg[d], 1.0f);
  }
}

// ---- dinv = rsqrt(deg + 1) in place ----
__global__ __launch_bounds__(256) void dinv_kernel(float* __restrict__ deg, int N) {
  int i = blockIdx.x * blockDim.x + threadIdx.x;
  if (i < N) deg[i] = rsqrtf(deg[i] + 1.0f);
}

// ---- fused front end: pert/basal linears + emb renorm + emb_trans + pert_base_trans ----
__global__ __launch_bounds__(256) void front_kernel(
    const float* __restrict__ x, const float* __restrict__ Emb,
    const float* __restrict__ Wp, const float* __restrict__ bp,
    const float* __restrict__ Wg, const float* __restrict__ bg,
    const float* __restrict__ bet, const float* __restrict__ bpb,
    const float* __restrict__ Wet, const float* __restrict__ Wpb,
    float* __restrict__ h0, int N, int NG) {
  __shared__ float sW[16384];   // [0,8192): Wet (128x64), [8192,16384): Wpb (128x64)
  for (int idx = threadIdx.x; idx < 8192; idx += 256) sW[idx] = Wet[idx];
  for (int idx = threadIdx.x; idx < 8192; idx += 256) sW[8192 + idx] = Wpb[idx];
  __syncthreads();
  int lane = threadIdx.x & 63;
  int wid  = threadIdx.x >> 6;
  float wp = Wp[lane], bpv = bp[lane], wg = Wg[lane], bgv = bg[lane];
  float betv = bet[lane], bpbv = bpb[lane];
  int wstride = gridDim.x * 4;
  for (int i = blockIdx.x * 4 + wid; i < N; i += wstride) {
    float xb = x[2 * i], xp = x[2 * i + 1];
    int gid = i % NG;
    float ev = Emb[gid * H + lane];
    float s = wave_sum(ev * ev);
    float nrm = sqrtf(s);
    float scale = fminf(1.0f, 1.0f / fmaxf(nrm, 1e-12f));
    ev *= scale;
    float base = fmaf(xb, wg, bgv);
    float pert = fmaf(xp, wp, bpv);
    float t = betv;
    #pragma unroll
    for (int k = 0; k < 64; ++k) t = fmaf(__shfl(base, k, 64), sW[k * H + lane], t);
    #pragma unroll
    for (int k = 0; k < 64; ++k) t = fmaf(__shfl(ev, k, 64), sW[(64 + k) * H + lane], t);
    float hh = bpbv;
    #pragma unroll
    for (int k = 0; k < 64; ++k) hh = fmaf(__shfl(t, k, 64), sW[8192 + k * H + lane], hh);
    #pragma unroll
    for (int k = 0; k < 64; ++k) hh = fmaf(__shfl(pert, k, 64), sW[8192 + (64 + k) * H + lane], hh);
    h0[i * H + lane] = hh;
  }
}

// ---- g = (h @ Wc) * dinv[i] ----
__global__ __launch_bounds__(256) void mm_kernel(const float* __restrict__ hin,
                                                 const float* __restrict__ Wc,
                                                 const float* __restrict__ dinv,
                                                 float* __restrict__ g, int N) {
  __shared__ float sW[4096];
  for (int idx = threadIdx.x; idx < 4096; idx += 256) sW[idx] = Wc[idx];
  __syncthreads();
  int lane = threadIdx.x & 63, wid = threadIdx.x >> 6;
  int wstride = gridDim.x * 4;
  for (int i = blockIdx.x * 4 + wid; i < N; i += wstride) {
    float hv = hin[i * H + lane];
    float a = 0.f;
    #pragma unroll
    for (int k = 0; k < 64; ++k) a = fmaf(__shfl(hv, k, 64), sW[k * H + lane], a);
    g[i * H + lane] = a * dinv[i];
  }
}

// ---- edge scatter: acc[dst] += g[src], wave per edge (lane = feature) ----
__global__ __launch_bounds__(256) void scatter_kernel(const float* __restrict__ g,
                                                      float* __restrict__ acc,
                                                      const int* __restrict__ ei, int E) {
  long long total = (long long)E * H;
  long long stride = (long long)gridDim.x * blockDim.x;
  for (long long t = (long long)blockIdx.x * blockDim.x + threadIdx.x; t < total; t += stride) {
    int e = (int)(t >> 6);
    int f = (int)(t & 63);
    int s = ei[e];
    int d = ei[E + e];
    atomicAdd(&acc[d * H + f], g[s * H + f]);
  }
}

// ---- epilogue: h = [relu](dinv[i]*(acc+g) + b) ----
__global__ __launch_bounds__(256) void finish_kernel(const float* __restrict__ acc,
                                                     const float* __restrict__ g,
                                                     const float* __restrict__ dinv,
                                                     const float* __restrict__ b,
                                                     float* __restrict__ hout,
                                                     int total, int relu) {
  int t = blockIdx.x * 256 + threadIdx.x;
  if (t >= total) return;
  int i = t >> 6;
  int f = t & 63;
  float v = fmaf(dinv[i], acc[t] + g[t], b[f]);
  if (relu) v = fmaxf(v, 0.f);
  hout[t] = v;
}

// ---- recovery MLP: relu(h@Wr1+br1) -> relu(@Wr2+br2) -> @Wr3+br3 + x[:,0] ----
__global__ __launch_bounds__(256) void mlp_kernel(const float* __restrict__ hin,
    const float* __restrict__ Wr1, const float* __restrict__ br1,
    const float* __restrict__ Wr2, const float* __restrict__ br2,
    const float* __restrict__ Wr3, const float* __restrict__ br3,
    const float* __restrict__ x, float* __restrict__ out, int N) {
  __shared__ float sW1[8192];   // Wr1: 64x128
  __shared__ float sW2[8192];   // Wr2: 128x64
  for (int idx = threadIdx.x; idx < 8192; idx += 256) sW1[idx] = Wr1[idx];
  for (int idx = threadIdx.x; idx < 8192; idx += 256) sW2[idx] = Wr2[idx];
  __syncthreads();
  int lane = threadIdx.x & 63, wid = threadIdx.x >> 6;
  float b1a = br1[lane], b1b = br1[64 + lane], b2 = br2[lane], w3 = Wr3[lane], b3 = br3[0];
  int wstride = gridDim.x * 4;
  for (int i = blockIdx.x * 4 + wid; i < N; i += wstride) {
    float hv = hin[i * H + lane];
    float r1a = b1a, r1b = b1b;
    #pragma unroll
    for (int k = 0; k < 64; ++k) {
      float hk = __shfl(hv, k, 64);
      r1a = fmaf(hk, sW1[k * 128 + lane], r1a);
      r1b = fmaf(hk, sW1[k * 128 + 64 + lane], r1b);
    }
    r1a = fmaxf(r1a, 0.f);
    r1b = fmaxf(r1b, 0.f);
    float r2 = b2;
    #pragma unroll
    for (int k = 0; k < 64; ++k) {
      r2 = fmaf(__shfl(r1a, k, 64), sW2[k * H + lane], r2);
      r2 = fmaf(__shfl(r1b, k, 64), sW2[(64 + k) * H + lane], r2);
    }
    r2 = fmaxf(r2, 0.f);
    float tot = wave_sum(r2 * w3);
    if (lane == 0) out[i] = tot + b3 + x[2 * i];
  }
}

extern "C" void kernel_launch(void* const* d_in, const int* in_sizes, int n_in,
                              void* d_out, int out_size, void* d_ws, size_t ws_size,
                              hipStream_t stream) {
  const float* x   = (const float*)d_in[0];
  const int*   ei  = (const int*)d_in[1];       // int32 per harness convention
  const float* Wp  = (const float*)d_in[2];
  const float* bp  = (const float*)d_in[3];
  const float* Wg  = (const float*)d_in[4];
  const float* bg  = (const float*)d_in[5];
  const float* Emb = (const float*)d_in[6];
  const float* Wet = (const float*)d_in[7];
  const float* bet = (const float*)d_in[8];
  const float* Wpb = (const float*)d_in[9];
  const float* bpb = (const float*)d_in[10];
  const float* Wc1 = (const float*)d_in[11];
  const float* bc1 = (const float*)d_in[12];
  const float* Wc2 = (const float*)d_in[13];
  const float* bc2 = (const float*)d_in[14];
  const float* Wr1 = (const float*)d_in[15];
  const float* br1 = (const float*)d_in[16];
  const float* Wr2 = (const float*)d_in[17];
  const float* br2 = (const float*)d_in[18];
  const float* Wr3 = (const float*)d_in[19];
  const float* br3 = (const float*)d_in[20];

  int N  = in_sizes[0] / 2;
  int E  = in_sizes[1] / 2;
  int NG = in_sizes[6] / H;
  size_t NH = (size_t)N * H;

  float* ws   = (float*)d_ws;
  float* dinv = ws;                                  // N floats (deg -> dinv in place)
  float* hA   = ws + (((size_t)N + 255) & ~(size_t)255);
  float* gB   = hA + NH;
  float* accC = gB + NH;

  int total = N * H;

  // degrees -> dinv
  hipMemsetAsync(dinv, 0, (size_t)N * sizeof(float), stream);
  deg_kernel<<<4096, 256, 0, stream>>>(ei, dinv, E);
  dinv_kernel<<<(N + 255) / 256, 256, 0, stream>>>(dinv, N);

  // fused front end -> hA
  front_kernel<<<1024, 256, 0, stream>>>(x, Emb, Wp, bp, Wg, bg, bet, bpb, Wet, Wpb, hA, N, NG);

  // GCN layer 1 (relu)
  mm_kernel<<<2048, 256, 0, stream>>>(hA, Wc1, dinv, gB, N);
  hipMemsetAsync(accC, 0, NH * sizeof(float), stream);
  scatter_kernel<<<8192, 256, 0, stream>>>(gB, accC, ei, E);
  finish_kernel<<<(total + 255) / 256, 256, 0, stream>>>(accC, gB, dinv, bc1, hA, total, 1);

  // GCN layer 2 (no relu)
  mm_kernel<<<2048, 256, 0, stream>>>(hA, Wc2, dinv, gB, N);
  hipMemsetAsync(accC, 0, NH * sizeof(float), stream);
  scatter_kernel<<<8192, 256, 0, stream>>>(gB, accC, ei, E);
  finish_kernel<<<(total + 255) / 256, 256, 0, stream>>>(accC, gB, dinv, bc2, hA, total, 0);

  // recovery MLP -> out
  mlp_kernel<<<1024, 256, 0, stream>>>(hA, Wr1, br1, Wr2, br2, Wr3, br3, x, (float*)d_out, N);
}

// Round 4
// 2159.901 us; speedup vs baseline: 1.9810x; 1.9810x over previous
//
#include <hip/hip_runtime.h>
#include <cstdint>

#define H 64
#define LDP 65   // padded LDS row stride (floats) -> conflict-free transpose

// ---- degree count ----
__global__ __launch_bounds__(256) void deg_kernel(const int* __restrict__ ei,
                                                  float* __restrict__ deg, int E) {
  int stride = gridDim.x * blockDim.x;
  for (int e = blockIdx.x * blockDim.x + threadIdx.x; e < E; e += stride) {
    atomicAdd(&deg[ei[E + e]], 1.0f);
  }
}

__global__ __launch_bounds__(256) void dinv_kernel(float* __restrict__ deg, int N) {
  int i = blockIdx.x * blockDim.x + threadIdx.x;
  if (i < N) deg[i] = rsqrtf(deg[i] + 1.0f);
}

// ---------- front end: lane = node, 64 nodes per wave/block ----------
// Reference-faithful: no precompute fold; full 128-deep concat matmuls.
__global__ __launch_bounds__(64) void front_kernel(
    const float* __restrict__ x, const float* __restrict__ Emb,
    const float* __restrict__ Wp, const float* __restrict__ bp,
    const float* __restrict__ Wg, const float* __restrict__ bg,
    const float* __restrict__ Wet, const float* __restrict__ bet,
    const float* __restrict__ Wpb, const float* __restrict__ bpb,
    float* __restrict__ h0, int NG) {
  __shared__ float sA[64 * LDP];
  const int lane = threadIdx.x;
  const int base = blockIdx.x * 64;
  const int r0 = lane >> 4, c = (lane & 15) * 4;

  // stage Emb rows (row r = node base+r, gid=(base+r)%NG), coalesced float4
  #pragma unroll
  for (int it = 0; it < 16; ++it) {
    int row = it * 4 + r0;
    int gid = (base + row) % NG;
    float4 v = *(const float4*)(Emb + (size_t)gid * H + c);
    float* p = sA + row * LDP + c;
    p[0] = v.x; p[1] = v.y; p[2] = v.z; p[3] = v.w;
  }
  __syncthreads();

  // per-node renorm scale
  float s = 0.f;
  for (int k = 0; k < H; ++k) { float v = sA[lane * LDP + k]; s = fmaf(v, v, s); }
  float scale = fminf(1.0f, 1.0f / fmaxf(sqrtf(s), 1e-12f));

  float x0 = x[2 * (base + lane)];
  float x1 = x[2 * (base + lane) + 1];

  // t = concat([base_emb, e_renormed]) @ Wet + bet
  float acc[64];
  #pragma unroll
  for (int j = 0; j < 64; ++j) acc[j] = bet[j];
  for (int k = 0; k < H; ++k) {          // base part: rows 0..63
    float bk = fmaf(x0, Wg[k], bg[k]);
    const float* w = Wet + (size_t)k * H;
    #pragma unroll
    for (int j = 0; j < 64; ++j) acc[j] = fmaf(bk, w[j], acc[j]);
  }
  for (int k = 0; k < H; ++k) {          // e part: rows 64..127
    float ek = sA[lane * LDP + k] * scale;
    const float* w = Wet + (size_t)(H + k) * H;
    #pragma unroll
    for (int j = 0; j < 64; ++j) acc[j] = fmaf(ek, w[j], acc[j]);
  }

  // h = concat([t, pert_emb]) @ Wpb + bpb   (t stays in registers)
  float h[64];
  #pragma unroll
  for (int j = 0; j < 64; ++j) h[j] = bpb[j];
  #pragma unroll
  for (int k = 0; k < H; ++k) {          // t part: rows 0..63
    float tk = acc[k];
    const float* w = Wpb + (size_t)k * H;
    #pragma unroll
    for (int j = 0; j < 64; ++j) h[j] = fmaf(tk, w[j], h[j]);
  }
  for (int k = 0; k < H; ++k) {          // pert part: rows 64..127
    float pk = fmaf(x1, Wp[k], bp[k]);
    const float* w = Wpb + (size_t)(H + k) * H;
    #pragma unroll
    for (int j = 0; j < 64; ++j) h[j] = fmaf(pk, w[j], h[j]);
  }

  // transpose back via sA, coalesced store
  __syncthreads();
  #pragma unroll
  for (int j = 0; j < 64; ++j) sA[lane * LDP + j] = h[j];
  __syncthreads();
  #pragma unroll
  for (int it = 0; it < 16; ++it) {
    int row = it * 4 + r0;
    const float* p = sA + row * LDP + c;
    *(float4*)(h0 + (size_t)(base + row) * H + c) = make_float4(p[0], p[1], p[2], p[3]);
  }
}

// ---------- g = (h @ Wc) * dinv, lane = node ----------
__global__ __launch_bounds__(64) void mm_kernel(
    const float* __restrict__ hin, const float* __restrict__ Wc,
    const float* __restrict__ dinv, float* __restrict__ g) {
  __shared__ float sA[64 * LDP];
  const int lane = threadIdx.x;
  const int base = blockIdx.x * 64;
  int r0 = lane >> 4, c = (lane & 15) * 4;
  #pragma unroll
  for (int it = 0; it < 16; ++it) {
    int row = it * 4 + r0;
    float4 v = *(const float4*)(hin + (size_t)(base + row) * H + c);
    float* p = sA + row * LDP + c;
    p[0] = v.x; p[1] = v.y; p[2] = v.z; p[3] = v.w;
  }
  __syncthreads();
  float acc[64];
  #pragma unroll
  for (int j = 0; j < 64; ++j) acc[j] = 0.f;
  #pragma unroll 2
  for (int k = 0; k < H; ++k) {
    float hk = sA[lane * LDP + k];
    const float* w = Wc + (size_t)k * H;
    #pragma unroll
    for (int j = 0; j < 64; ++j) acc[j] = fmaf(hk, w[j], acc[j]);
  }
  float dv = dinv[base + lane];
  __syncthreads();
  #pragma unroll
  for (int j = 0; j < 64; ++j) sA[lane * LDP + j] = acc[j] * dv;
  __syncthreads();
  #pragma unroll
  for (int it = 0; it < 16; ++it) {
    int row = it * 4 + r0;
    const float* p = sA + row * LDP + c;
    *(float4*)(g + (size_t)(base + row) * H + c) = make_float4(p[0], p[1], p[2], p[3]);
  }
}

// ---- edge scatter: acc[dst] += g[src], lane = feature ----
__global__ __launch_bounds__(256) void scatter_kernel(const float* __restrict__ g,
                                                      float* __restrict__ acc,
                                                      const int* __restrict__ ei, int E) {
  long long total = (long long)E * H;
  long long stride = (long long)gridDim.x * blockDim.x;
  for (long long t = (long long)blockIdx.x * blockDim.x + threadIdx.x; t < total; t += stride) {
    int e = (int)(t >> 6);
    int f = (int)(t & 63);
    int s = ei[e];
    int d = ei[E + e];
    atomicAdd(&acc[(size_t)d * H + f], g[(size_t)s * H + f]);
  }
}

// ---- epilogue: h = [relu](dinv[i]*(acc+g) + b) ----
__global__ __launch_bounds__(256) void finish_kernel(const float* __restrict__ acc,
                                                     const float* __restrict__ g,
                                                     const float* __restrict__ dinv,
                                                     const float* __restrict__ b,
                                                     float* __restrict__ hout,
                                                     int total, int relu) {
  int t = blockIdx.x * 256 + threadIdx.x;
  if (t >= total) return;
  int i = t >> 6;
  int f = t & 63;
  float v = fmaf(dinv[i], acc[t] + g[t], b[f]);
  if (relu) v = fmaxf(v, 0.f);
  hout[t] = v;
}

// ---------- recovery MLP, lane = node ----------
__global__ __launch_bounds__(64) void mlp_kernel(
    const float* __restrict__ hin,
    const float* __restrict__ Wr1, const float* __restrict__ br1,
    const float* __restrict__ Wr2, const float* __restrict__ br2,
    const float* __restrict__ Wr3, const float* __restrict__ br3,
    const float* __restrict__ x, float* __restrict__ out) {
  __shared__ float sA[64 * LDP];
  __shared__ float sB[64 * 129];
  const int lane = threadIdx.x;
  const int base = blockIdx.x * 64;
  int r0 = lane >> 4, c = (lane & 15) * 4;
  #pragma unroll
  for (int it = 0; it < 16; ++it) {
    int row = it * 4 + r0;
    float4 v = *(const float4*)(hin + (size_t)(base + row) * H + c);
    float* p = sA + row * LDP + c;
    p[0] = v.x; p[1] = v.y; p[2] = v.z; p[3] = v.w;
  }
  __syncthreads();

  float a[64], b[64];
  #pragma unroll
  for (int j = 0; j < 64; ++j) { a[j] = br1[j]; b[j] = br1[64 + j]; }
  #pragma unroll 2
  for (int k = 0; k < H; ++k) {
    float hk = sA[lane * LDP + k];
    const float* w = Wr1 + (size_t)k * 128;
    #pragma unroll
    for (int j = 0; j < 64; ++j) a[j] = fmaf(hk, w[j], a[j]);
    #pragma unroll
    for (int j = 0; j < 64; ++j) b[j] = fmaf(hk, w[64 + j], b[j]);
  }
  #pragma unroll
  for (int j = 0; j < 64; ++j) sB[lane * 129 + j] = fmaxf(a[j], 0.f);
  #pragma unroll
  for (int j = 0; j < 64; ++j) sB[lane * 129 + 64 + j] = fmaxf(b[j], 0.f);

  float cacc[64];
  #pragma unroll
  for (int j = 0; j < 64; ++j) cacc[j] = br2[j];
  #pragma unroll 2
  for (int k = 0; k < 128; ++k) {
    float rk = sB[lane * 129 + k];
    const float* w = Wr2 + (size_t)k * H;
    #pragma unroll
    for (int j = 0; j < 64; ++j) cacc[j] = fmaf(rk, w[j], cacc[j]);
  }

  float o = 0.f;
  #pragma unroll
  for (int j = 0; j < 64; ++j) o = fmaf(fmaxf(cacc[j], 0.f), Wr3[j], o);
  int i = base + lane;
  out[i] = o + br3[0] + x[2 * i];
}

extern "C" void kernel_launch(void* const* d_in, const int* in_sizes, int n_in,
                              void* d_out, int out_size, void* d_ws, size_t ws_size,
                              hipStream_t stream) {
  const float* x   = (const float*)d_in[0];
  const int*   ei  = (const int*)d_in[1];
  const float* Wp  = (const float*)d_in[2];
  const float* bp  = (const float*)d_in[3];
  const float* Wg  = (const float*)d_in[4];
  const float* bg  = (const float*)d_in[5];
  const float* Emb = (const float*)d_in[6];
  const float* Wet = (const float*)d_in[7];
  const float* bet = (const float*)d_in[8];
  const float* Wpb = (const float*)d_in[9];
  const float* bpb = (const float*)d_in[10];
  const float* Wc1 = (const float*)d_in[11];
  const float* bc1 = (const float*)d_in[12];
  const float* Wc2 = (const float*)d_in[13];
  const float* bc2 = (const float*)d_in[14];
  const float* Wr1 = (const float*)d_in[15];
  const float* br1 = (const float*)d_in[16];
  const float* Wr2 = (const float*)d_in[17];
  const float* br2 = (const float*)d_in[18];
  const float* Wr3 = (const float*)d_in[19];
  const float* br3 = (const float*)d_in[20];

  int N  = in_sizes[0] / 2;
  int E  = in_sizes[1] / 2;
  int NG = in_sizes[6] / H;
  size_t NH = (size_t)N * H;
  size_t Npad = ((size_t)N + 255) & ~(size_t)255;

  float* ws   = (float*)d_ws;
  float* dinv = ws;               // N floats
  float* hA   = ws + Npad;
  float* gB   = hA + NH;
  float* accC = gB + NH;

  int total = N * H;
  int nt = N / 64;

  hipMemsetAsync(dinv, 0, (size_t)N * sizeof(float), stream);
  deg_kernel<<<4096, 256, 0, stream>>>(ei, dinv, E);
  dinv_kernel<<<(N + 255) / 256, 256, 0, stream>>>(dinv, N);

  front_kernel<<<nt, 64, 0, stream>>>(x, Emb, Wp, bp, Wg, bg, Wet, bet, Wpb, bpb, hA, NG);

  // GCN layer 1 (relu)
  mm_kernel<<<nt, 64, 0, stream>>>(hA, Wc1, dinv, gB);
  hipMemsetAsync(accC, 0, NH * sizeof(float), stream);
  scatter_kernel<<<8192, 256, 0, stream>>>(gB, accC, ei, E);
  finish_kernel<<<(total + 255) / 256, 256, 0, stream>>>(accC, gB, dinv, bc1, hA, total, 1);

  // GCN layer 2 (no relu)
  mm_kernel<<<nt, 64, 0, stream>>>(hA, Wc2, dinv, gB);
  hipMemsetAsync(accC, 0, NH * sizeof(float), stream);
  scatter_kernel<<<8192, 256, 0, stream>>>(gB, accC, ei, E);
  finish_kernel<<<(total + 255) / 256, 256, 0, stream>>>(accC, gB, dinv, bc2, hA, total, 0);

  mlp_kernel<<<nt, 64, 0, stream>>>(hA, Wr1, br1, Wr2, br2, Wr3, br3, x, (float*)d_out);
}

// Round 5
// 1187.127 us; speedup vs baseline: 3.6043x; 1.8194x over previous
//
#include <hip/hip_runtime.h>
#include <cstdint>

#define H 64
#define LDP 65   // padded LDS row stride -> conflict-free transpose
#define CH 1024  // elements per scan block

// ---- int degree histogram ----
__global__ __launch_bounds__(256) void deg_kernel(const int* __restrict__ ei,
                                                  int* __restrict__ deg, int E) {
  int stride = gridDim.x * blockDim.x;
  for (int e = blockIdx.x * blockDim.x + threadIdx.x; e < E; e += stride) {
    atomicAdd(&deg[ei[E + e]], 1);
  }
}

__global__ __launch_bounds__(256) void dinv_kernel(const int* __restrict__ deg,
                                                   float* __restrict__ dinv, int N) {
  int i = blockIdx.x * blockDim.x + threadIdx.x;
  if (i < N) dinv[i] = rsqrtf((float)deg[i] + 1.0f);
}

// ---- scan stage A: per-1024-chunk exclusive prefix (intra-block) + block totals ----
__global__ __launch_bounds__(256) void scanA_kernel(const int* __restrict__ deg,
                                                    int* __restrict__ pre,
                                                    int* __restrict__ blockTot, int N) {
  __shared__ int sa[256], sb[256];
  int t = threadIdx.x;
  int base = blockIdx.x * CH + t * 4;
  int v[4]; int sum = 0;
  #pragma unroll
  for (int k = 0; k < 4; ++k) { int idx = base + k; v[k] = (idx < N) ? deg[idx] : 0; sum += v[k]; }
  sa[t] = sum;
  __syncthreads();
  int* pin = sa; int* pout = sb;
  #pragma unroll
  for (int off = 1; off < 256; off <<= 1) {
    int val = pin[t];
    if (t >= off) val += pin[t - off];
    pout[t] = val;
    __syncthreads();
    int* tmp = pin; pin = pout; pout = tmp;
  }
  int excl = pin[t] - sum;
  if (t == 255) blockTot[blockIdx.x] = pin[255];
  int run = excl;
  #pragma unroll
  for (int k = 0; k < 4; ++k) { int idx = base + k; if (idx < N) pre[idx] = run; run += v[k]; }
}

// ---- scan stage B: single-block exclusive scan of blockTot (nb <= 1024), in place ----
__global__ __launch_bounds__(256) void scanB_kernel(int* __restrict__ blockTot, int nb) {
  __shared__ int sa[256], sb[256];
  int t = threadIdx.x;
  int base = t * 4;
  int v[4]; int sum = 0;
  #pragma unroll
  for (int k = 0; k < 4; ++k) { int idx = base + k; v[k] = (idx < nb) ? blockTot[idx] : 0; sum += v[k]; }
  sa[t] = sum;
  __syncthreads();
  int* pin = sa; int* pout = sb;
  #pragma unroll
  for (int off = 1; off < 256; off <<= 1) {
    int val = pin[t];
    if (t >= off) val += pin[t - off];
    pout[t] = val;
    __syncthreads();
    int* tmp = pin; pin = pout; pout = tmp;
  }
  int excl = pin[t] - sum;
  int run = excl;
  #pragma unroll
  for (int k = 0; k < 4; ++k) { int idx = base + k; if (idx < nb) blockTot[idx] = run; run += v[k]; }
}

// ---- scan stage C: add block offsets -> rowStart complete ----
__global__ __launch_bounds__(256) void scanC_kernel(int* __restrict__ pre,
                                                    const int* __restrict__ blockTot, int N) {
  int off = blockTot[blockIdx.x];
  int base = blockIdx.x * CH + threadIdx.x * 4;
  #pragma unroll
  for (int k = 0; k < 4; ++k) { int idx = base + k; if (idx < N) pre[idx] += off; }
}

// ---- CSR fill: csr[rowStart[dst] + slot] = src ----
__global__ __launch_bounds__(256) void fill_kernel(const int* __restrict__ ei,
                                                   const int* __restrict__ rowStart,
                                                   int* __restrict__ fillc,
                                                   int* __restrict__ csr, int E) {
  int stride = gridDim.x * blockDim.x;
  for (int e = blockIdx.x * blockDim.x + threadIdx.x; e < E; e += stride) {
    int d = ei[E + e];
    int pos = rowStart[d] + atomicAdd(&fillc[d], 1);
    csr[pos] = ei[e];
  }
}

// ---------- front end: lane = node ----------
__global__ __launch_bounds__(64) void front_kernel(
    const float* __restrict__ x, const float* __restrict__ Emb,
    const float* __restrict__ Wp, const float* __restrict__ bp,
    const float* __restrict__ Wg, const float* __restrict__ bg,
    const float* __restrict__ Wet, const float* __restrict__ bet,
    const float* __restrict__ Wpb, const float* __restrict__ bpb,
    float* __restrict__ h0, int NG) {
  __shared__ float sA[64 * LDP];
  const int lane = threadIdx.x;
  const int base = blockIdx.x * 64;
  const int r0 = lane >> 4, c = (lane & 15) * 4;

  #pragma unroll
  for (int it = 0; it < 16; ++it) {
    int row = it * 4 + r0;
    int gid = (base + row) % NG;
    float4 v = *(const float4*)(Emb + (size_t)gid * H + c);
    float* p = sA + row * LDP + c;
    p[0] = v.x; p[1] = v.y; p[2] = v.z; p[3] = v.w;
  }
  __syncthreads();

  float s = 0.f;
  for (int k = 0; k < H; ++k) { float v = sA[lane * LDP + k]; s = fmaf(v, v, s); }
  float scale = fminf(1.0f, 1.0f / fmaxf(sqrtf(s), 1e-12f));

  float x0 = x[2 * (base + lane)];
  float x1 = x[2 * (base + lane) + 1];

  float acc[64];
  #pragma unroll
  for (int j = 0; j < 64; ++j) acc[j] = bet[j];
  for (int k = 0; k < H; ++k) {
    float bk = fmaf(x0, Wg[k], bg[k]);
    const float* w = Wet + (size_t)k * H;
    #pragma unroll
    for (int j = 0; j < 64; ++j) acc[j] = fmaf(bk, w[j], acc[j]);
  }
  for (int k = 0; k < H; ++k) {
    float ek = sA[lane * LDP + k] * scale;
    const float* w = Wet + (size_t)(H + k) * H;
    #pragma unroll
    for (int j = 0; j < 64; ++j) acc[j] = fmaf(ek, w[j], acc[j]);
  }

  float h[64];
  #pragma unroll
  for (int j = 0; j < 64; ++j) h[j] = bpb[j];
  #pragma unroll
  for (int k = 0; k < H; ++k) {
    float tk = acc[k];
    const float* w = Wpb + (size_t)k * H;
    #pragma unroll
    for (int j = 0; j < 64; ++j) h[j] = fmaf(tk, w[j], h[j]);
  }
  for (int k = 0; k < H; ++k) {
    float pk = fmaf(x1, Wp[k], bp[k]);
    const float* w = Wpb + (size_t)(H + k) * H;
    #pragma unroll
    for (int j = 0; j < 64; ++j) h[j] = fmaf(pk, w[j], h[j]);
  }

  __syncthreads();
  #pragma unroll
  for (int j = 0; j < 64; ++j) sA[lane * LDP + j] = h[j];
  __syncthreads();
  #pragma unroll
  for (int it = 0; it < 16; ++it) {
    int row = it * 4 + r0;
    const float* p = sA + row * LDP + c;
    *(float4*)(h0 + (size_t)(base + row) * H + c) = make_float4(p[0], p[1], p[2], p[3]);
  }
}

// ---------- g = (h @ Wc) * dinv, lane = node ----------
__global__ __launch_bounds__(64) void mm_kernel(
    const float* __restrict__ hin, const float* __restrict__ Wc,
    const float* __restrict__ dinv, float* __restrict__ g) {
  __shared__ float sA[64 * LDP];
  const int lane = threadIdx.x;
  const int base = blockIdx.x * 64;
  int r0 = lane >> 4, c = (lane & 15) * 4;
  #pragma unroll
  for (int it = 0; it < 16; ++it) {
    int row = it * 4 + r0;
    float4 v = *(const float4*)(hin + (size_t)(base + row) * H + c);
    float* p = sA + row * LDP + c;
    p[0] = v.x; p[1] = v.y; p[2] = v.z; p[3] = v.w;
  }
  __syncthreads();
  float acc[64];
  #pragma unroll
  for (int j = 0; j < 64; ++j) acc[j] = 0.f;
  #pragma unroll 2
  for (int k = 0; k < H; ++k) {
    float hk = sA[lane * LDP + k];
    const float* w = Wc + (size_t)k * H;
    #pragma unroll
    for (int j = 0; j < 64; ++j) acc[j] = fmaf(hk, w[j], acc[j]);
  }
  float dv = dinv[base + lane];
  __syncthreads();
  #pragma unroll
  for (int j = 0; j < 64; ++j) sA[lane * LDP + j] = acc[j] * dv;
  __syncthreads();
  #pragma unroll
  for (int it = 0; it < 16; ++it) {
    int row = it * 4 + r0;
    const float* p = sA + row * LDP + c;
    *(float4*)(g + (size_t)(base + row) * H + c) = make_float4(p[0], p[1], p[2], p[3]);
  }
}

// ---------- CSR gather + fused epilogue: hout = [relu](dinv[i]*(sum_src g[src] + g[i]) + b) ----------
__global__ __launch_bounds__(256) void gather_kernel(
    const float* __restrict__ g, const int* __restrict__ csr,
    const int* __restrict__ rowStart, const int* __restrict__ deg,
    const float* __restrict__ dinv, const float* __restrict__ b,
    float* __restrict__ hout, int N, int relu) {
  const int lane = threadIdx.x & 63;
  int wid = blockIdx.x * 4 + (threadIdx.x >> 6);
  int nw = gridDim.x * 4;
  float bias = b[lane];
  for (int i = wid; i < N; i += nw) {
    int start = rowStart[i];
    int cnt = deg[i];
    float acc = 0.f;
    int e = 0;
    for (; e + 4 <= cnt; e += 4) {
      int s0 = csr[start + e];
      int s1 = csr[start + e + 1];
      int s2 = csr[start + e + 2];
      int s3 = csr[start + e + 3];
      float v0 = g[(size_t)s0 * H + lane];
      float v1 = g[(size_t)s1 * H + lane];
      float v2 = g[(size_t)s2 * H + lane];
      float v3 = g[(size_t)s3 * H + lane];
      acc += (v0 + v1) + (v2 + v3);
    }
    for (; e < cnt; ++e) {
      int s = csr[start + e];
      acc += g[(size_t)s * H + lane];
    }
    float v = fmaf(dinv[i], acc + g[(size_t)i * H + lane], bias);
    if (relu) v = fmaxf(v, 0.f);
    hout[(size_t)i * H + lane] = v;
  }
}

// ---------- recovery MLP, lane = node ----------
__global__ __launch_bounds__(64) void mlp_kernel(
    const float* __restrict__ hin,
    const float* __restrict__ Wr1, const float* __restrict__ br1,
    const float* __restrict__ Wr2, const float* __restrict__ br2,
    const float* __restrict__ Wr3, const float* __restrict__ br3,
    const float* __restrict__ x, float* __restrict__ out) {
  __shared__ float sA[64 * LDP];
  __shared__ float sB[64 * 129];
  const int lane = threadIdx.x;
  const int base = blockIdx.x * 64;
  int r0 = lane >> 4, c = (lane & 15) * 4;
  #pragma unroll
  for (int it = 0; it < 16; ++it) {
    int row = it * 4 + r0;
    float4 v = *(const float4*)(hin + (size_t)(base + row) * H + c);
    float* p = sA + row * LDP + c;
    p[0] = v.x; p[1] = v.y; p[2] = v.z; p[3] = v.w;
  }
  __syncthreads();

  float a[64], b[64];
  #pragma unroll
  for (int j = 0; j < 64; ++j) { a[j] = br1[j]; b[j] = br1[64 + j]; }
  #pragma unroll 2
  for (int k = 0; k < H; ++k) {
    float hk = sA[lane * LDP + k];
    const float* w = Wr1 + (size_t)k * 128;
    #pragma unroll
    for (int j = 0; j < 64; ++j) a[j] = fmaf(hk, w[j], a[j]);
    #pragma unroll
    for (int j = 0; j < 64; ++j) b[j] = fmaf(hk, w[64 + j], b[j]);
  }
  #pragma unroll
  for (int j = 0; j < 64; ++j) sB[lane * 129 + j] = fmaxf(a[j], 0.f);
  #pragma unroll
  for (int j = 0; j < 64; ++j) sB[lane * 129 + 64 + j] = fmaxf(b[j], 0.f);

  float cacc[64];
  #pragma unroll
  for (int j = 0; j < 64; ++j) cacc[j] = br2[j];
  #pragma unroll 2
  for (int k = 0; k < 128; ++k) {
    float rk = sB[lane * 129 + k];
    const float* w = Wr2 + (size_t)k * H;
    #pragma unroll
    for (int j = 0; j < 64; ++j) cacc[j] = fmaf(rk, w[j], cacc[j]);
  }

  float o = 0.f;
  #pragma unroll
  for (int j = 0; j < 64; ++j) o = fmaf(fmaxf(cacc[j], 0.f), Wr3[j], o);
  int i = base + lane;
  out[i] = o + br3[0] + x[2 * i];
}

extern "C" void kernel_launch(void* const* d_in, const int* in_sizes, int n_in,
                              void* d_out, int out_size, void* d_ws, size_t ws_size,
                              hipStream_t stream) {
  const float* x   = (const float*)d_in[0];
  const int*   ei  = (const int*)d_in[1];
  const float* Wp  = (const float*)d_in[2];
  const float* bp  = (const float*)d_in[3];
  const float* Wg  = (const float*)d_in[4];
  const float* bg  = (const float*)d_in[5];
  const float* Emb = (const float*)d_in[6];
  const float* Wet = (const float*)d_in[7];
  const float* bet = (const float*)d_in[8];
  const float* Wpb = (const float*)d_in[9];
  const float* bpb = (const float*)d_in[10];
  const float* Wc1 = (const float*)d_in[11];
  const float* bc1 = (const float*)d_in[12];
  const float* Wc2 = (const float*)d_in[13];
  const float* bc2 = (const float*)d_in[14];
  const float* Wr1 = (const float*)d_in[15];
  const float* br1 = (const float*)d_in[16];
  const float* Wr2 = (const float*)d_in[17];
  const float* br2 = (const float*)d_in[18];
  const float* Wr3 = (const float*)d_in[19];
  const float* br3 = (const float*)d_in[20];

  int N  = in_sizes[0] / 2;
  int E  = in_sizes[1] / 2;
  int NG = in_sizes[6] / H;
  size_t NH = (size_t)N * H;
  size_t Npad = ((size_t)N + 255) & ~(size_t)255;
  int nb = (N + CH - 1) / CH;

  // workspace layout (all 4-byte elements; Npad multiples keep 16B alignment)
  int*   degI     = (int*)d_ws;                // Npad
  int*   rowStart = degI + Npad;               // Npad
  int*   fillC    = rowStart + Npad;           // Npad
  int*   blockTot = fillC + Npad;              // 1024
  int*   csr      = blockTot + 1024;           // E (E % 256 == 0)
  float* dinv     = (float*)(csr + E);         // Npad
  float* hA       = dinv + Npad;               // NH
  float* gB       = hA + NH;                   // NH

  int nt = N / 64;

  // ---- CSR build ----
  hipMemsetAsync(degI, 0, Npad * sizeof(int), stream);
  hipMemsetAsync(fillC, 0, Npad * sizeof(int), stream);
  deg_kernel<<<4096, 256, 0, stream>>>(ei, degI, E);
  scanA_kernel<<<nb, 256, 0, stream>>>(degI, rowStart, blockTot, N);
  scanB_kernel<<<1, 256, 0, stream>>>(blockTot, nb);
  scanC_kernel<<<nb, 256, 0, stream>>>(rowStart, blockTot, N);
  dinv_kernel<<<(N + 255) / 256, 256, 0, stream>>>(degI, dinv, N);
  fill_kernel<<<4096, 256, 0, stream>>>(ei, rowStart, fillC, csr, E);

  // ---- front end ----
  front_kernel<<<nt, 64, 0, stream>>>(x, Emb, Wp, bp, Wg, bg, Wet, bet, Wpb, bpb, hA, NG);

  // ---- GCN layer 1 (relu) ----
  mm_kernel<<<nt, 64, 0, stream>>>(hA, Wc1, dinv, gB);
  gather_kernel<<<2048, 256, 0, stream>>>(gB, csr, rowStart, degI, dinv, bc1, hA, N, 1);

  // ---- GCN layer 2 (no relu) ----
  mm_kernel<<<nt, 64, 0, stream>>>(hA, Wc2, dinv, gB);
  gather_kernel<<<2048, 256, 0, stream>>>(gB, csr, rowStart, degI, dinv, bc2, hA, N, 0);

  // ---- recovery MLP ----
  mlp_kernel<<<nt, 64, 0, stream>>>(hA, Wr1, br1, Wr2, br2, Wr3, br3, x, (float*)d_out);
}